// Round 12
// baseline (203.111 us; speedup 1.0000x reference)
//
#include <hip/hip_runtime.h>
#include <hip/hip_bf16.h>
#include <stdint.h>

#define DM   1024
#define NH   16
#define DKK  64
#define BB   4
#define SSEQ 2048
#define MTOT 8192

typedef __attribute__((ext_vector_type(8))) __bf16 bf16x8;
typedef __attribute__((ext_vector_type(2))) float f32x2;
typedef __attribute__((ext_vector_type(4))) float f32x4;
typedef __attribute__((ext_vector_type(16))) float f32x16;
typedef __attribute__((ext_vector_type(4))) unsigned int u32x4;

__device__ __forceinline__ unsigned short f2bf(float f) {
  union { float f; unsigned int u; } v; v.f = f;
  unsigned int r = v.u + 0x7FFFu + ((v.u >> 16) & 1u);
  return (unsigned short)(r >> 16);
}

__device__ __forceinline__ unsigned int cvtpk(float lo, float hi) {
  unsigned int r;
  asm("v_cvt_pk_bf16_f32 %0, %1, %2" : "=v"(r) : "v"(lo), "v"(hi));
  return r;
}

__device__ __forceinline__ void gld16(const void* g, void* l) {
  typedef __attribute__((address_space(1))) const unsigned int gq_t;
  typedef __attribute__((address_space(3))) unsigned int lq_t;
  __builtin_amdgcn_global_load_lds((gq_t*)g, (lq_t*)l, 16, 0, 0);
}

// ---------------------------------------------------------------- cast fp32->bf16
__global__ __launch_bounds__(256)
void cast5(const float* __restrict__ x,  const float* __restrict__ wq,
           const float* __restrict__ wk, const float* __restrict__ wv,
           const float* __restrict__ wo,
           unsigned short* __restrict__ xb,  unsigned short* __restrict__ wqb,
           unsigned short* __restrict__ wkb, unsigned short* __restrict__ wvb,
           unsigned short* __restrict__ wob)
{
  const int blk = blockIdx.x;
  const float* src; unsigned short* dst; int base;
  if (blk < 512) { src = x; dst = xb; base = blk * 4096; }
  else {
    const int w = (blk - 512) >> 6, i = (blk - 512) & 63;
    base = i * 4096;
    src = (w==0) ? wq : (w==1) ? wk : (w==2) ? wv : wo;
    dst = (w==0) ? wqb : (w==1) ? wkb : (w==2) ? wvb : wob;
  }
  #pragma unroll
  for (int it = 0; it < 16; ++it) {
    const int idx = base + it*256 + (int)threadIdx.x;
    const float4 v = ((const float4*)src)[idx];
    ushort4 o; o.x = f2bf(v.x); o.y = f2bf(v.y); o.z = f2bf(v.z); o.w = f2bf(v.w);
    ((ushort4*)dst)[idx] = o;
  }
}

// ---------------------------------------------------------------- GEMM-NT 128x128x64, dbuf + T2 swizzle
// (frozen from R10/R11: ~905 TF/dispatch -- at the 2-phase-structure ceiling)
// MODE 0: K -> bf16 [B,H,S,Dk]   MODE 1: final -> fp32
// MODE 2: V -> V' chunks [bh][S/16][64d][16]   MODE 3: Q -> bf16, pre-scaled
template<int MODE>
__global__ __launch_bounds__(256, 2)
void gemm_nt(const unsigned short* __restrict__ A,
             const unsigned short* __restrict__ Bw,
             const float* __restrict__ bias,
             void* __restrict__ Cp)
{
  __shared__ unsigned short As[2][8192];       // 2 x 16KB
  __shared__ unsigned short Bs[2][8192];       // 2 x 16KB  (total 64KB)
  int wg = blockIdx.x;
  wg = (wg & 7) * 64 + (wg >> 3);              // XCD swizzle (512 % 8 == 0)
  const int bm = wg >> 3, bn = wg & 7;
  const int m0 = bm * 128, n0 = bn * 128;
  const int tid = threadIdx.x;
  const int lane = tid & 63, wv = tid >> 6;
  const int wr = wv >> 1, wc = wv & 1;
  const int lr = lane & 15, lg = lane >> 4;

  const f32x4 fz = {0.f, 0.f, 0.f, 0.f};
  f32x4 acc[4][4];
  #pragma unroll
  for (int i = 0; i < 4; ++i)
    #pragma unroll
    for (int j = 0; j < 4; ++j) acc[i][j] = fz;

  const int srow = wv*32 + (lane >> 3);
  const int scolb = ((lane & 7) * 16) ^ ((lane >> 3) << 4);   // swizzled byte col
  const unsigned short* Abase = A  + (size_t)(m0 + srow)*DM + (scolb >> 1);
  const unsigned short* Bbase = Bw + (size_t)(n0 + srow)*DM + (scolb >> 1);

  #define GSTAGE(bufi, kt)  {                                               \
    const int kc = (kt) * 64;                                               \
    _Pragma("unroll")                                                       \
    for (int c = 0; c < 4; ++c) {                                           \
      gld16(Abase + (size_t)c*8*DM + kc,                                    \
            (char*)&As[bufi][0] + wv*4096 + c*1024);                        \
      gld16(Bbase + (size_t)c*8*DM + kc,                                    \
            (char*)&Bs[bufi][0] + wv*4096 + c*1024);                        \
    } }

  GSTAGE(0, 0);
  __syncthreads();

  for (int kt = 0; kt < 16; ++kt) {
    const int buf = kt & 1;
    if (kt < 15) GSTAGE(buf ^ 1, kt + 1);      // prefetch flies during compute
    #pragma unroll
    for (int kk = 0; kk < 2; ++kk) {           // kk-outer: K=32 slice each
      bf16x8 af[4], bf[4];
      #pragma unroll
      for (int i = 0; i < 4; ++i) {
        const int row = wr*64 + i*16 + lr;
        af[i] = *(const bf16x8*)((char*)&As[buf][0] + row*128
                 + ((kk*64 + lg*16) ^ ((lr & 7) << 4)));
      }
      #pragma unroll
      for (int j = 0; j < 4; ++j) {
        const int row = wc*64 + j*16 + lr;
        bf[j] = *(const bf16x8*)((char*)&Bs[buf][0] + row*128
                 + ((kk*64 + lg*16) ^ ((lr & 7) << 4)));
      }
      #pragma unroll
      for (int i = 0; i < 4; ++i)
        #pragma unroll
        for (int j = 0; j < 4; ++j)
          acc[i][j] = __builtin_amdgcn_mfma_f32_16x16x32_bf16(af[i], bf[j], acc[i][j], 0, 0, 0);
    }
    __syncthreads();                           // one barrier per K-step
  }
  #undef GSTAGE

  #pragma unroll
  for (int j = 0; j < 4; ++j) {
    const int n = n0 + wc*64 + j*16 + lr;
    const float bvv = bias[n];
    #pragma unroll
    for (int i = 0; i < 4; ++i) {
      #pragma unroll
      for (int r = 0; r < 4; ++r) {
        const int m = m0 + wr*64 + i*16 + lg*4 + r;
        float v = acc[i][j][r] + bvv;
        if (MODE == 3) v *= 0.18033688011112042f;    // log2(e)/8 pre-scale for Q
        if (MODE == 0 || MODE == 3) {
          const int b = m >> 11, s = m & 2047, h = n >> 6, d = n & 63;
          ((unsigned short*)Cp)[(size_t)((b*NH + h)*SSEQ + s)*DKK + d] = f2bf(v);
        } else if (MODE == 2) {
          const int b = m >> 11, s = m & 2047, h = n >> 6, d = n & 63;
          ((unsigned short*)Cp)[(size_t)(b*NH + h)*(SSEQ*DKK)
                                + (((s >> 4)*64 + d) << 4) + (s & 15)] = f2bf(v);
        } else {
          ((float*)Cp)[(size_t)m*DM + n] = v;
        }
      }
    }
  }
}

// ---------------------------------------------------------------- flash attention v9 (attn1d + VALU diet)
// 2048 blocks = 8 XCD x 8 bh x 32 q-tiles; 2 waves x 32 q; KVBLK=64 shared K dbuf.
// Diet vs R11: (1) s written by first MFMA with persistent ZEROV C-in (no per-half
// zero-init movs); (2) kv loop unroll-2 -> buf compile-time -> ds_read offsets fold
// to immediates; (3) kv-invariant swizzled bo[4] precomputed; (4) f32x2 l-accum
// (v_pk_add_f32 target). Math identical to R11.
__device__ __forceinline__ u32x4 packP(const f32x16& sv, const int j, const int hi)
{
  const int rb = j * 8;
  const unsigned int a0 = cvtpk(sv[rb+0], sv[rb+1]);
  const unsigned int a1 = cvtpk(sv[rb+2], sv[rb+3]);
  const unsigned int b0 = cvtpk(sv[rb+4], sv[rb+5]);
  const unsigned int b1 = cvtpk(sv[rb+6], sv[rb+7]);
  const unsigned int s0_ = hi ? a0 : b0;
  const unsigned int s1_ = hi ? a1 : b1;
  const unsigned int r0 = __shfl_xor(s0_, 32, 64);
  const unsigned int r1 = __shfl_xor(s1_, 32, 64);
  u32x4 pk;
  pk[0] = hi ? r0 : a0;
  pk[1] = hi ? r1 : a1;
  pk[2] = hi ? b0 : r0;
  pk[3] = hi ? b1 : r1;
  return pk;
}

__global__ __launch_bounds__(128, 2)
void attn1d(const unsigned short* __restrict__ Q,
            const unsigned short* __restrict__ K,
            const unsigned short* __restrict__ Vp,
            unsigned short* __restrict__ AO)
{
  __shared__ unsigned short Ks[2][4096];           // 16KB: K dbuf only
  const int flat = blockIdx.x;
  const int xcd = flat & 7, idx = flat >> 3;       // idx in [0,256)
  const int bh = xcd*8 + (idx >> 5), qt = idx & 31;
  const int b = bh >> 4, h = bh & 15;
  const int tid = threadIdx.x, lane = tid & 63, wv = tid >> 6;
  const int l31 = lane & 31, hi = lane >> 5;
  const int q0 = qt*64 + wv*32;                    // wave's 32-q column
  const size_t hoff = (size_t)bh * SSEQ * DKK;
  const unsigned short* Qg = Q  + hoff;
  const unsigned short* Kg = K  + hoff;
  const unsigned short* Vb = Vp + hoff;            // V' [S/16][64 d][16]

  bf16x8 qf[4];
  {
    const unsigned short* qr = Qg + (size_t)(q0 + l31)*DKK + hi*8;
    #pragma unroll
    for (int ks = 0; ks < 4; ++ks)
      qf[ks] = *(const bf16x8*)(qr + ks*16);
  }

  f32x16 oA0, oA1, ZEROV;
  f32x2 lacc2[4];
  #pragma unroll
  for (int r = 0; r < 16; ++r) { oA0[r]=0.f; oA1[r]=0.f; ZEROV[r]=0.f; }
  #pragma unroll
  for (int r = 0; r < 4; ++r) lacc2[r] = (f32x2){0.f, 0.f};

  const int sbase = wv*4096 + lane*16;
  const int cbyte = hi * 16;
  const int swz = (l31 & 7) << 4;
  // kv-invariant swizzled K-frag byte offsets (within one 4KB half)
  const int bo_[4] = { l31*128 + ((0*32 + cbyte) ^ swz),
                       l31*128 + ((1*32 + cbyte) ^ swz),
                       l31*128 + ((2*32 + cbyte) ^ swz),
                       l31*128 + ((3*32 + cbyte) ^ swz) };

  #define STAGE(bufi, kv0)                                                        \
    _Pragma("unroll")                                                             \
    for (int it = 0; it < 4; ++it) {                                              \
      const int LB  = sbase + it*1024;                                            \
      const int row = LB >> 7;                                                    \
      const int cb  = (LB & 127) ^ ((row & 7) << 4);                              \
      gld16(Kg + (size_t)((kv0) + row)*DKK + (cb >> 1),                           \
            (char*)&Ks[bufi][0] + LB);                                            \
    }

  STAGE(0, 0);
  __syncthreads();

  #pragma unroll 2
  for (int kv = 0; kv < 32; ++kv) {
    const int buf = kv & 1;                        // compile-time under unroll-2
    const int kv0 = kv * 64;
    if (kv < 31) { STAGE(buf ^ 1, kv0 + 64); }
    const char* KsB = (const char*)&Ks[buf][0];
    const unsigned short* vbase = Vb + (size_t)kv*4096 + l31*16 + hi*8;

    #pragma unroll
    for (int hf = 0; hf < 2; ++hf) {
      bf16x8 vf0[2], vf1[2];
      #pragma unroll
      for (int j = 0; j < 2; ++j) {
        vf0[j] = *(const bf16x8*)(vbase + (2*hf + j)*1024);
        vf1[j] = *(const bf16x8*)(vbase + (2*hf + j)*1024 + 512);
      }

      // K frags (offsets fold: bo_[ks] + hf*4096 imm under unrolled buf/hf)
      bf16x8 kf[4];
      #pragma unroll
      for (int ks = 0; ks < 4; ++ks)
        kf[ks] = *(const bf16x8*)(KsB + hf*4096 + bo_[ks]);

      __builtin_amdgcn_s_setprio(1);
      f32x16 s = __builtin_amdgcn_mfma_f32_32x32x16_bf16(kf[0], qf[0], ZEROV, 0, 0, 0);
      #pragma unroll
      for (int ks = 1; ks < 4; ++ks)
        s = __builtin_amdgcn_mfma_f32_32x32x16_bf16(kf[ks], qf[ks], s, 0, 0, 0);
      __builtin_amdgcn_s_setprio(0);

      // softmax: P = exp2(S') (Q pre-scaled); paired l-accumulate
      #pragma unroll
      for (int r = 0; r < 16; ++r)
        s[r] = __builtin_amdgcn_exp2f(s[r]);
      #pragma unroll
      for (int i = 0; i < 8; ++i)
        lacc2[i & 3] += (f32x2){s[2*i], s[2*i + 1]};

      __builtin_amdgcn_s_setprio(1);
      #pragma unroll
      for (int j = 0; j < 2; ++j) {
        const u32x4 pk = packP(s, j, hi);
        const bf16x8 pb = __builtin_bit_cast(bf16x8, pk);
        oA0 = __builtin_amdgcn_mfma_f32_32x32x16_bf16(vf0[j], pb, oA0, 0, 0, 0);
        oA1 = __builtin_amdgcn_mfma_f32_32x32x16_bf16(vf1[j], pb, oA1, 0, 0, 0);
      }
      __builtin_amdgcn_s_setprio(0);
    }
    __syncthreads();
  }

  float lA = ((lacc2[0][0]+lacc2[0][1]) + (lacc2[1][0]+lacc2[1][1]))
           + ((lacc2[2][0]+lacc2[2][1]) + (lacc2[3][0]+lacc2[3][1]));
  lA += __shfl_xor(lA, 32, 64);
  const float inv = 1.f / lA;

  char* lds = (char*)&Ks[0][0] + wv*4096;          // 32 rows x 128B
  {
    const int row = l31;
    #pragma unroll
    for (int db = 0; db < 2; ++db) {
      const f32x16& o = db ? oA1 : oA0;
      #pragma unroll
      for (int r = 0; r < 16; r += 2) {
        const int d = db*32 + (r & 3) + 8*(r >> 2) + 4*hi;
        *(unsigned int*)(lds + row*128 + ((d*2) ^ swz)) = cvtpk(o[r]*inv, o[r+1]*inv);
      }
    }
  }
  __syncthreads();
  {
    const int q = q0 + l31;
    unsigned short* orow = AO + (size_t)(b*SSEQ + q)*DM + h*DKK;
    #pragma unroll
    for (int it = 0; it < 4; ++it) {
      const int c16 = hi + 2*it;
      const uint4 v = *(const uint4*)(lds + l31*128 + ((c16*16) ^ swz));
      *(uint4*)(orow + c16*8) = v;
    }
  }
  #undef STAGE
}

// ---------------------------------------------------------------- launch
extern "C" void kernel_launch(void* const* d_in, const int* in_sizes, int n_in,
                              void* d_out, int out_size, void* d_ws, size_t ws_size,
                              hipStream_t stream)
{
  (void)in_sizes; (void)n_in; (void)out_size; (void)ws_size;
  const float* x  = (const float*)d_in[0];
  const float* Wq = (const float*)d_in[1];
  const float* bq = (const float*)d_in[2];
  const float* Wk = (const float*)d_in[3];
  const float* bk = (const float*)d_in[4];
  const float* Wv = (const float*)d_in[5];
  const float* bv = (const float*)d_in[6];
  const float* Wo = (const float*)d_in[7];
  const float* bo = (const float*)d_in[8];

  char* ws = (char*)d_ws;
  unsigned short* xb  = (unsigned short*)(ws + 0);         // reused as AO
  unsigned short* wqb = (unsigned short*)(ws + 16777216);
  unsigned short* wkb = (unsigned short*)(ws + 18874368);
  unsigned short* wvb = (unsigned short*)(ws + 20971520);
  unsigned short* wob = (unsigned short*)(ws + 23068672);
  unsigned short* Qb  = (unsigned short*)(ws + 25165824);
  unsigned short* Kb  = (unsigned short*)(ws + 41943040);
  unsigned short* Vpb = (unsigned short*)(ws + 58720256);  // V' chunk layout
  unsigned short* AO  = xb;

  cast5<<<768, 256, 0, stream>>>(x, Wq, Wk, Wv, Wo, xb, wqb, wkb, wvb, wob);
  gemm_nt<3><<<512, 256, 0, stream>>>(xb, wqb, bq, Qb);
  gemm_nt<0><<<512, 256, 0, stream>>>(xb, wkb, bk, Kb);
  gemm_nt<2><<<512, 256, 0, stream>>>(xb, wvb, bv, Vpb);
  attn1d<<<2048, 128, 0, stream>>>(Qb, Kb, Vpb, AO);
  gemm_nt<1><<<512, 256, 0, stream>>>(AO, wob, bo, (float*)d_out);
}

// Round 13
// 193.915 us; speedup vs baseline: 1.0474x; 1.0474x over previous
//
#include <hip/hip_runtime.h>
#include <hip/hip_bf16.h>
#include <stdint.h>

#define DM   1024
#define NH   16
#define DKK  64
#define BB   4
#define SSEQ 2048
#define MTOT 8192

typedef __attribute__((ext_vector_type(8))) __bf16 bf16x8;
typedef __attribute__((ext_vector_type(4))) float f32x4;
typedef __attribute__((ext_vector_type(16))) float f32x16;
typedef __attribute__((ext_vector_type(4))) unsigned int u32x4;

__device__ __forceinline__ unsigned short f2bf(float f) {
  union { float f; unsigned int u; } v; v.f = f;
  unsigned int r = v.u + 0x7FFFu + ((v.u >> 16) & 1u);
  return (unsigned short)(r >> 16);
}

__device__ __forceinline__ unsigned int cvtpk(float lo, float hi) {
  unsigned int r;
  asm("v_cvt_pk_bf16_f32 %0, %1, %2" : "=v"(r) : "v"(lo), "v"(hi));
  return r;
}

__device__ __forceinline__ void gld16(const void* g, void* l) {
  typedef __attribute__((address_space(1))) const unsigned int gq_t;
  typedef __attribute__((address_space(3))) unsigned int lq_t;
  __builtin_amdgcn_global_load_lds((gq_t*)g, (lq_t*)l, 16, 0, 0);
}

// ---------------------------------------------------------------- cast fp32->bf16
__global__ __launch_bounds__(256)
void cast5(const float* __restrict__ x,  const float* __restrict__ wq,
           const float* __restrict__ wk, const float* __restrict__ wv,
           const float* __restrict__ wo,
           unsigned short* __restrict__ xb,  unsigned short* __restrict__ wqb,
           unsigned short* __restrict__ wkb, unsigned short* __restrict__ wvb,
           unsigned short* __restrict__ wob)
{
  const int blk = blockIdx.x;
  const float* src; unsigned short* dst; int base;
  if (blk < 512) { src = x; dst = xb; base = blk * 4096; }
  else {
    const int w = (blk - 512) >> 6, i = (blk - 512) & 63;
    base = i * 4096;
    src = (w==0) ? wq : (w==1) ? wk : (w==2) ? wv : wo;
    dst = (w==0) ? wqb : (w==1) ? wkb : (w==2) ? wvb : wob;
  }
  #pragma unroll
  for (int it = 0; it < 16; ++it) {
    const int idx = base + it*256 + (int)threadIdx.x;
    const float4 v = ((const float4*)src)[idx];
    ushort4 o; o.x = f2bf(v.x); o.y = f2bf(v.y); o.z = f2bf(v.z); o.w = f2bf(v.w);
    ((ushort4*)dst)[idx] = o;
  }
}

// ---------------------------------------------------------------- GEMM-NT 128x128x64, dbuf + T2 swizzle
// (R10/R11-proven: ~905 TF/dispatch -- at the 2-phase-structure ceiling)
// MODE 0: K -> bf16 [B,H,S,Dk]   MODE 1: final -> fp32
// MODE 2: V -> V' chunks [bh][S/16][64d][16]   MODE 3: Q -> bf16, pre-scaled
template<int MODE>
__global__ __launch_bounds__(256, 2)
void gemm_nt(const unsigned short* __restrict__ A,
             const unsigned short* __restrict__ Bw,
             const float* __restrict__ bias,
             void* __restrict__ Cp)
{
  __shared__ unsigned short As[2][8192];       // 2 x 16KB
  __shared__ unsigned short Bs[2][8192];       // 2 x 16KB  (total 64KB)
  int wg = blockIdx.x;
  wg = (wg & 7) * 64 + (wg >> 3);              // XCD swizzle (512 % 8 == 0)
  const int bm = wg >> 3, bn = wg & 7;
  const int m0 = bm * 128, n0 = bn * 128;
  const int tid = threadIdx.x;
  const int lane = tid & 63, wv = tid >> 6;
  const int wr = wv >> 1, wc = wv & 1;
  const int lr = lane & 15, lg = lane >> 4;

  const f32x4 fz = {0.f, 0.f, 0.f, 0.f};
  f32x4 acc[4][4];
  #pragma unroll
  for (int i = 0; i < 4; ++i)
    #pragma unroll
    for (int j = 0; j < 4; ++j) acc[i][j] = fz;

  const int srow = wv*32 + (lane >> 3);
  const int scolb = ((lane & 7) * 16) ^ ((lane >> 3) << 4);   // swizzled byte col
  const unsigned short* Abase = A  + (size_t)(m0 + srow)*DM + (scolb >> 1);
  const unsigned short* Bbase = Bw + (size_t)(n0 + srow)*DM + (scolb >> 1);

  #define GSTAGE(bufi, kt)  {                                               \
    const int kc = (kt) * 64;                                               \
    _Pragma("unroll")                                                       \
    for (int c = 0; c < 4; ++c) {                                           \
      gld16(Abase + (size_t)c*8*DM + kc,                                    \
            (char*)&As[bufi][0] + wv*4096 + c*1024);                        \
      gld16(Bbase + (size_t)c*8*DM + kc,                                    \
            (char*)&Bs[bufi][0] + wv*4096 + c*1024);                        \
    } }

  GSTAGE(0, 0);
  __syncthreads();

  for (int kt = 0; kt < 16; ++kt) {
    const int buf = kt & 1;
    if (kt < 15) GSTAGE(buf ^ 1, kt + 1);      // prefetch flies during compute
    #pragma unroll
    for (int kk = 0; kk < 2; ++kk) {           // kk-outer: K=32 slice each
      bf16x8 af[4], bf[4];
      #pragma unroll
      for (int i = 0; i < 4; ++i) {
        const int row = wr*64 + i*16 + lr;
        af[i] = *(const bf16x8*)((char*)&As[buf][0] + row*128
                 + ((kk*64 + lg*16) ^ ((lr & 7) << 4)));
      }
      #pragma unroll
      for (int j = 0; j < 4; ++j) {
        const int row = wc*64 + j*16 + lr;
        bf[j] = *(const bf16x8*)((char*)&Bs[buf][0] + row*128
                 + ((kk*64 + lg*16) ^ ((lr & 7) << 4)));
      }
      #pragma unroll
      for (int i = 0; i < 4; ++i)
        #pragma unroll
        for (int j = 0; j < 4; ++j)
          acc[i][j] = __builtin_amdgcn_mfma_f32_16x16x32_bf16(af[i], bf[j], acc[i][j], 0, 0, 0);
    }
    __syncthreads();                           // one barrier per K-step
  }
  #undef GSTAGE

  #pragma unroll
  for (int j = 0; j < 4; ++j) {
    const int n = n0 + wc*64 + j*16 + lr;
    const float bvv = bias[n];
    #pragma unroll
    for (int i = 0; i < 4; ++i) {
      #pragma unroll
      for (int r = 0; r < 4; ++r) {
        const int m = m0 + wr*64 + i*16 + lg*4 + r;
        float v = acc[i][j][r] + bvv;
        if (MODE == 3) v *= 0.18033688011112042f;    // log2(e)/8 pre-scale for Q
        if (MODE == 0 || MODE == 3) {
          const int b = m >> 11, s = m & 2047, h = n >> 6, d = n & 63;
          ((unsigned short*)Cp)[(size_t)((b*NH + h)*SSEQ + s)*DKK + d] = f2bf(v);
        } else if (MODE == 2) {
          const int b = m >> 11, s = m & 2047, h = n >> 6, d = n & 63;
          ((unsigned short*)Cp)[(size_t)(b*NH + h)*(SSEQ*DKK)
                                + (((s >> 4)*64 + d) << 4) + (s & 15)] = f2bf(v);
        } else {
          ((float*)Cp)[(size_t)m*DM + n] = v;
        }
      }
    }
  }
}

// ---------------------------------------------------------------- flash attention (R11-proven attn1d, bit-exact revert)
// 2048 blocks = 8 XCD x 8 bh x 32 q-tiles; 2 waves x 32 q; KVBLK=64 shared K dbuf.
// 90 us, 763 TF incl. softmax. Bracketed local optimum: 2w/32kv=118, 1w/32kv=103,
// (128,4)-spill=173, VALU-diet=103 all worse. Do not micro-edit (R12 lesson).
__device__ __forceinline__ u32x4 packP(const f32x16& sv, const int j, const int hi)
{
  const int rb = j * 8;
  const unsigned int a0 = cvtpk(sv[rb+0], sv[rb+1]);
  const unsigned int a1 = cvtpk(sv[rb+2], sv[rb+3]);
  const unsigned int b0 = cvtpk(sv[rb+4], sv[rb+5]);
  const unsigned int b1 = cvtpk(sv[rb+6], sv[rb+7]);
  const unsigned int s0_ = hi ? a0 : b0;
  const unsigned int s1_ = hi ? a1 : b1;
  const unsigned int r0 = __shfl_xor(s0_, 32, 64);
  const unsigned int r1 = __shfl_xor(s1_, 32, 64);
  u32x4 pk;
  pk[0] = hi ? r0 : a0;
  pk[1] = hi ? r1 : a1;
  pk[2] = hi ? b0 : r0;
  pk[3] = hi ? b1 : r1;
  return pk;
}

__global__ __launch_bounds__(128, 2)
void attn1d(const unsigned short* __restrict__ Q,
            const unsigned short* __restrict__ K,
            const unsigned short* __restrict__ Vp,
            unsigned short* __restrict__ AO)
{
  __shared__ unsigned short Ks[2][4096];           // 16KB: K dbuf only
  const int flat = blockIdx.x;
  const int xcd = flat & 7, idx = flat >> 3;       // idx in [0,256)
  const int bh = xcd*8 + (idx >> 5), qt = idx & 31;
  const int b = bh >> 4, h = bh & 15;
  const int tid = threadIdx.x, lane = tid & 63, wv = tid >> 6;
  const int l31 = lane & 31, hi = lane >> 5;
  const int q0 = qt*64 + wv*32;                    // wave's 32-q column
  const size_t hoff = (size_t)bh * SSEQ * DKK;
  const unsigned short* Qg = Q  + hoff;
  const unsigned short* Kg = K  + hoff;
  const unsigned short* Vb = Vp + hoff;            // V' [S/16][64 d][16]

  bf16x8 qf[4];
  {
    const unsigned short* qr = Qg + (size_t)(q0 + l31)*DKK + hi*8;
    #pragma unroll
    for (int ks = 0; ks < 4; ++ks)
      qf[ks] = *(const bf16x8*)(qr + ks*16);
  }

  f32x16 oA0, oA1;
  float lacc[8];
  #pragma unroll
  for (int r = 0; r < 16; ++r) { oA0[r]=0.f; oA1[r]=0.f; }
  #pragma unroll
  for (int r = 0; r < 8; ++r) lacc[r] = 0.f;

  const int sbase = wv*4096 + lane*16;
  const int cbyte = hi * 16;

  #define STAGE(bufi, kv0)                                                        \
    _Pragma("unroll")                                                             \
    for (int it = 0; it < 4; ++it) {                                              \
      const int LB  = sbase + it*1024;                                            \
      const int row = LB >> 7;                                                    \
      const int cb  = (LB & 127) ^ ((row & 7) << 4);                              \
      gld16(Kg + (size_t)((kv0) + row)*DKK + (cb >> 1),                           \
            (char*)&Ks[bufi][0] + LB);                                            \
    }

  STAGE(0, 0);
  __syncthreads();

  for (int kv = 0; kv < 32; ++kv) {
    const int buf = kv & 1;
    const int kv0 = kv * 64;
    if (kv < 31) { STAGE(buf ^ 1, kv0 + 64); }
    const char* KsB = (const char*)&Ks[buf][0];
    const unsigned short* vbase = Vb + (kv0 >> 4)*1024 + l31*16 + hi*8;

    #pragma unroll
    for (int hf = 0; hf < 2; ++hf) {
      bf16x8 vf0[2], vf1[2];
      #pragma unroll
      for (int j = 0; j < 2; ++j) {
        vf0[j] = *(const bf16x8*)(vbase + (2*hf + j)*1024);
        vf1[j] = *(const bf16x8*)(vbase + (2*hf + j)*1024 + 512);
      }

      f32x16 s;
      #pragma unroll
      for (int r = 0; r < 16; ++r) s[r] = 0.f;
      __builtin_amdgcn_s_setprio(1);
      #pragma unroll
      for (int ks = 0; ks < 4; ++ks) {
        const int bo = l31*128 + ((ks*32 + cbyte) ^ ((l31 & 7) << 4));
        const bf16x8 kf = *(const bf16x8*)(KsB + hf*4096 + bo);
        s = __builtin_amdgcn_mfma_f32_32x32x16_bf16(kf, qf[ks], s, 0, 0, 0);
      }
      __builtin_amdgcn_s_setprio(0);

      #pragma unroll
      for (int r = 0; r < 16; ++r) {
        s[r] = __builtin_amdgcn_exp2f(s[r]);
        lacc[r & 7] += s[r];
      }

      __builtin_amdgcn_s_setprio(1);
      #pragma unroll
      for (int j = 0; j < 2; ++j) {
        const u32x4 pk = packP(s, j, hi);
        const bf16x8 pb = __builtin_bit_cast(bf16x8, pk);
        oA0 = __builtin_amdgcn_mfma_f32_32x32x16_bf16(vf0[j], pb, oA0, 0, 0, 0);
        oA1 = __builtin_amdgcn_mfma_f32_32x32x16_bf16(vf1[j], pb, oA1, 0, 0, 0);
      }
      __builtin_amdgcn_s_setprio(0);
    }
    __syncthreads();
  }

  float lA = ((lacc[0]+lacc[1])+(lacc[2]+lacc[3]))
           + ((lacc[4]+lacc[5])+(lacc[6]+lacc[7]));
  lA += __shfl_xor(lA, 32, 64);
  const float inv = 1.f / lA;

  char* lds = (char*)&Ks[0][0] + wv*4096;          // 32 rows x 128B
  {
    const int row = l31;
    const int swz = (l31 & 7) << 4;
    #pragma unroll
    for (int db = 0; db < 2; ++db) {
      const f32x16& o = db ? oA1 : oA0;
      #pragma unroll
      for (int r = 0; r < 16; r += 2) {
        const int d = db*32 + (r & 3) + 8*(r >> 2) + 4*hi;
        *(unsigned int*)(lds + row*128 + ((d*2) ^ swz)) = cvtpk(o[r]*inv, o[r+1]*inv);
      }
    }
  }
  __syncthreads();
  {
    const int q = q0 + l31;
    unsigned short* orow = AO + (size_t)(b*SSEQ + q)*DM + h*DKK;
    const int swz = (l31 & 7) << 4;
    #pragma unroll
    for (int it = 0; it < 4; ++it) {
      const int c16 = hi + 2*it;
      const uint4 v = *(const uint4*)(lds + l31*128 + ((c16*16) ^ swz));
      *(uint4*)(orow + c16*8) = v;
    }
  }
  #undef STAGE
}

// ---------------------------------------------------------------- launch
extern "C" void kernel_launch(void* const* d_in, const int* in_sizes, int n_in,
                              void* d_out, int out_size, void* d_ws, size_t ws_size,
                              hipStream_t stream)
{
  (void)in_sizes; (void)n_in; (void)out_size; (void)ws_size;
  const float* x  = (const float*)d_in[0];
  const float* Wq = (const float*)d_in[1];
  const float* bq = (const float*)d_in[2];
  const float* Wk = (const float*)d_in[3];
  const float* bk = (const float*)d_in[4];
  const float* Wv = (const float*)d_in[5];
  const float* bv = (const float*)d_in[6];
  const float* Wo = (const float*)d_in[7];
  const float* bo = (const float*)d_in[8];

  char* ws = (char*)d_ws;
  unsigned short* xb  = (unsigned short*)(ws + 0);         // reused as AO
  unsigned short* wqb = (unsigned short*)(ws + 16777216);
  unsigned short* wkb = (unsigned short*)(ws + 18874368);
  unsigned short* wvb = (unsigned short*)(ws + 20971520);
  unsigned short* wob = (unsigned short*)(ws + 23068672);
  unsigned short* Qb  = (unsigned short*)(ws + 25165824);
  unsigned short* Kb  = (unsigned short*)(ws + 41943040);
  unsigned short* Vpb = (unsigned short*)(ws + 58720256);  // V' chunk layout
  unsigned short* AO  = xb;

  cast5<<<768, 256, 0, stream>>>(x, Wq, Wk, Wv, Wo, xb, wqb, wkb, wvb, wob);
  gemm_nt<3><<<512, 256, 0, stream>>>(xb, wqb, bq, Qb);
  gemm_nt<0><<<512, 256, 0, stream>>>(xb, wkb, bk, Kb);
  gemm_nt<2><<<512, 256, 0, stream>>>(xb, wvb, bv, Vpb);
  attn1d<<<2048, 128, 0, stream>>>(Qb, Kb, Vpb, AO);
  gemm_nt<1><<<512, 256, 0, stream>>>(AO, wob, bo, (float*)d_out);
}